// Round 6
// baseline (93.169 us; speedup 1.0000x reference)
//
#include <hip/hip_runtime.h>

#define N 128
#define DIM 8192
#define NN (N * N)      // 16384
#define ZSPLIT 32       // K split: 32 chunks of 256
#define NW 16           // waves in finalize block
#define GSTRIDE 130     // LDS gm row stride (fallback solver)
#define NSTR 65         // per-class LDS row stride: 65%32=1 -> conflict-free col reads

// ---------------- wave-sync helpers ----------------------------------------
__device__ __forceinline__ void wave_fence() {
    __threadfence_block();
    __builtin_amdgcn_wave_barrier();
}
__device__ __forceinline__ double embed_key(double v, int j) {
    long long b = __double_as_longlong(v);
    return __longlong_as_double((b & ~127LL) | (long long)j);
}

// ---------------- Stage 1: dot partials + norm partials (split-K) -----------
// grid (4,4,32): 32x32 tile, K-chunk 256. 2x2 register tile per thread.
// Stores DOT products; d2 assembled downstream as sqA + sqB - 2*dot.
__global__ __launch_bounds__(256) void d2_partial(const float* __restrict__ A,
                                                  const float* __restrict__ B,
                                                  float* __restrict__ d2p,
                                                  float* __restrict__ sqAp,
                                                  float* __restrict__ sqBp) {
    __shared__ float As[32][68];
    __shared__ float Bk[64][36];
    const int tid = threadIdx.x;
    const int bi = blockIdx.x, bj = blockIdx.y, bz = blockIdx.z;
    const int tx = tid & 15, ty = tid >> 4;
    const int row0 = bi * 32, col0 = bj * 32;
    const int kbase = bz * 256;

    // norm-partial prelude (edge blocks only): 32 rows x 8 segs x 32 floats
    if (bj == 0) {
        const int r = tid >> 3, seg = tid & 7;
        const float* pa = &A[(row0 + r) * DIM + kbase + seg * 32];
        float s = 0.f;
        #pragma unroll
        for (int u = 0; u < 8; ++u) {
            float4 v = *(const float4*)&pa[u * 4];
            s = fmaf(v.x, v.x, fmaf(v.y, v.y, fmaf(v.z, v.z, fmaf(v.w, v.w, s))));
        }
        #pragma unroll
        for (int o = 1; o < 8; o <<= 1) s += __shfl_xor(s, o, 64);
        if (seg == 0) sqAp[bz * 128 + row0 + r] = s;
    }
    if (bi == 0) {
        const int r = tid >> 3, seg = tid & 7;
        const float* pb = &B[(col0 + r) * DIM + kbase + seg * 32];
        float s = 0.f;
        #pragma unroll
        for (int u = 0; u < 8; ++u) {
            float4 v = *(const float4*)&pb[u * 4];
            s = fmaf(v.x, v.x, fmaf(v.y, v.y, fmaf(v.z, v.z, fmaf(v.w, v.w, s))));
        }
        #pragma unroll
        for (int o = 1; o < 8; o <<= 1) s += __shfl_xor(s, o, 64);
        if (seg == 0) sqBp[bz * 128 + col0 + r] = s;
    }

    float a00 = 0.f, a01 = 0.f, a10 = 0.f, a11 = 0.f;
    for (int it = 0; it < 4; ++it) {
        const int k0 = kbase + it * 64;
        __syncthreads();
        #pragma unroll
        for (int s = 0; s < 2; ++s) {
            int e = tid + s * 256;
            int r = e >> 4, q = e & 15;
            *(float4*)&As[r][q * 4] = *(const float4*)&A[(row0 + r) * DIM + k0 + q * 4];
        }
        #pragma unroll
        for (int s = 0; s < 2; ++s) {
            int r = tid & 31;
            int kq = (tid >> 5) + s * 8;
            float4 b4 = *(const float4*)&B[(col0 + r) * DIM + k0 + kq * 4];
            Bk[kq * 4 + 0][r] = b4.x;
            Bk[kq * 4 + 1][r] = b4.y;
            Bk[kq * 4 + 2][r] = b4.z;
            Bk[kq * 4 + 3][r] = b4.w;
        }
        __syncthreads();
        #pragma unroll
        for (int kk = 0; kk < 64; kk += 4) {
            float x0[4], x1[4];
            *(float4*)x0 = *(const float4*)&As[2 * ty][kk];
            *(float4*)x1 = *(const float4*)&As[2 * ty + 1][kk];
            float y[4][2];
            #pragma unroll
            for (int q = 0; q < 4; ++q)
                *(float2*)y[q] = *(const float2*)&Bk[kk + q][2 * tx];
            #pragma unroll
            for (int q = 0; q < 4; ++q) {
                a00 = fmaf(x0[q], y[q][0], a00);
                a01 = fmaf(x0[q], y[q][1], a01);
                a10 = fmaf(x1[q], y[q][0], a10);
                a11 = fmaf(x1[q], y[q][1], a11);
            }
        }
    }
    const int o0 = (row0 + 2 * ty) * N + col0 + 2 * tx;
    float* dst = d2p + bz * NN;
    *(float2*)&dst[o0]     = make_float2(a00, a01);
    *(float2*)&dst[o0 + N] = make_float2(a10, a11);
}

// ---------------- Stage 2: fused reduce+transform + per-class solve ---------
// 64 blocks x 256 threads, stream-ordered only (no device fences).
//  A: z-reduce + norm combine -> gm slice + flag (all threads)
//  B: wave-0 decomposition; gather own class submatrix from d2p (all threads,
//     same-label entries so g = max(d2,0)); wave-0 JV solve -> cls_val[blk].
// Solver never reads gm or flags; finalize discards cls_val when flagged.
__global__ __launch_bounds__(256) void reduce_solve(const float* __restrict__ d2p,
                                                    const float* __restrict__ sqAp,
                                                    const float* __restrict__ sqBp,
                                                    const int* __restrict__ t1,
                                                    const int* __restrict__ t2,
                                                    float* __restrict__ gm,
                                                    int* __restrict__ flagarr,
                                                    double* __restrict__ cls_val) {
    __shared__ float ncls[64 * NSTR];   // 16.6 KB
    __shared__ float sqA_l[128], sqB_l[128];
    __shared__ int bf;
    __shared__ int rowl[64], coll[64], rcnt[64], ccnt[64], tasks64[64], clm[64];
    __shared__ int sT, sn, sm, shave;

    const int tid = threadIdx.x;
    const int blk = blockIdx.x;

    // ---------------- Phase A: gm slice + flag ------------------------------
    if (tid == 0) bf = 0;
    {   // stage reduced norm vectors
        const int c = tid & 127;
        const float* src = (tid < 128) ? (sqBp + c) : (sqAp + c);
        float t0 = 0.f, t1_ = 0.f, t2_ = 0.f, t3 = 0.f, t4 = 0.f, t5 = 0.f, t6 = 0.f, t7 = 0.f;
        #pragma unroll
        for (int z = 0; z < ZSPLIT; z += 8) {
            t0 += src[(z + 0) * 128]; t1_ += src[(z + 1) * 128];
            t2_ += src[(z + 2) * 128]; t3 += src[(z + 3) * 128];
            t4 += src[(z + 4) * 128]; t5 += src[(z + 5) * 128];
            t6 += src[(z + 6) * 128]; t7 += src[(z + 7) * 128];
        }
        float s = ((t0 + t1_) + (t2_ + t3)) + ((t4 + t5) + (t6 + t7));
        if (tid < 128) sqB_l[c] = s; else sqA_l[c] = s;
    }
    const int o = blk * 256 + tid;
    float dot;
    {
        const float* p = d2p + o;
        float s0 = 0.f, s1 = 0.f, s2 = 0.f, s3 = 0.f, s4 = 0.f, s5 = 0.f, s6 = 0.f, s7 = 0.f;
        #pragma unroll
        for (int z = 0; z < ZSPLIT; z += 8) {
            s0 += p[(z + 0) * NN]; s1 += p[(z + 1) * NN];
            s2 += p[(z + 2) * NN]; s3 += p[(z + 3) * NN];
            s4 += p[(z + 4) * NN]; s5 += p[(z + 5) * NN];
            s6 += p[(z + 6) * NN]; s7 += p[(z + 7) * NN];
        }
        dot = ((s0 + s1) + (s2 + s3)) + ((s4 + s5) + (s6 + s7));
    }
    __syncthreads();
    {
        const int i = o >> 7, j = o & 127;
        const float s = sqA_l[i] + sqB_l[j] - 2.f * dot;
        const int l1 = t1[i], l2 = t2[j];
        const bool same = (l1 == l2);
        float g = same ? fmaxf(s, 0.f) : fmaxf(200.f - s, 0.f);
        gm[o] = g;
        bool bad = (!same && g > 0.f) || l1 < 0 || l1 > 63 || l2 < 0 || l2 > 63;
        unsigned long long m = __ballot(bad);
        if ((tid & 63) == 0 && m) atomicOr(&bf, 1);
    }
    __syncthreads();
    if (tid == 0) flagarr[blk] = bf;

    // ---------------- Phase B: decomposition (wave 0) -----------------------
    if (tid < 64) {
        const int lane = tid;
        const int l1a = t1[lane] & 63, l1b = t1[lane + 64] & 63;
        const int l2a = t2[lane] & 63, l2b = t2[lane + 64] & 63;
        rcnt[lane] = 0; ccnt[lane] = 0;
        wave_fence();
        atomicAdd(&rcnt[l1a], 1); atomicAdd(&rcnt[l1b], 1);
        atomicAdd(&ccnt[l2a], 1); atomicAdd(&ccnt[l2b], 1);
        wave_fence();
        int ntasks;
        {
            int R = rcnt[lane], C = ccnt[lane];
            bool small = (R > 0) && (C > 0) && (R <= 64) && (C <= 64);
            unsigned long long ms = __ballot(small);
            if (small) tasks64[__popcll(ms & ((1ull << lane) - 1))] = lane;
            ntasks = (int)__popcll(ms);
        }
        wave_fence();
        const bool have = (blk < ntasks);
        if (have) {
            const int c = tasks64[blk];
            const unsigned long long mlt = (1ull << lane) - 1;
            unsigned long long b1 = __ballot(l1a == c);
            unsigned long long b2 = __ballot(l1b == c);
            if (l1a == c) rowl[__popcll(b1 & mlt)] = lane;
            if (l1b == c) rowl[__popcll(b1) + __popcll(b2 & mlt)] = lane + 64;
            const int Rn = (int)(__popcll(b1) + __popcll(b2));
            unsigned long long c1 = __ballot(l2a == c);
            unsigned long long c2 = __ballot(l2b == c);
            if (l2a == c) coll[__popcll(c1 & mlt)] = lane;
            if (l2b == c) coll[__popcll(c1) + __popcll(c2 & mlt)] = lane + 64;
            const int Cn = (int)(__popcll(c1) + __popcll(c2));
            if (lane == 0) {
                const bool T = (Rn > Cn);
                sT = T ? 1 : 0;
                sn = T ? Cn : Rn;
                sm = T ? Rn : Cn;
            }
        }
        if (lane == 0) shave = have ? 1 : 0;
    }
    __syncthreads();
    if (!shave) {
        if (tid == 0) cls_val[blk] = 0.0;
        return;
    }

    // gather class submatrix from d2p (4 lanes/entry, 8 z each); same-label
    // entries so the transform is g = max(d2, 0).
    {
        const int n_ = sn, m_ = sm, T = sT;
        const int tot = n_ * m_;
        const int sub = tid & 3;
        for (int e = tid >> 2; e < tot; e += 64) {
            const int i = e / m_, j = e - i * m_;
            const int gr = T ? rowl[j] : rowl[i];
            const int gc = T ? coll[i] : coll[j];
            const float* p = d2p + gr * N + gc + sub * 8 * NN;
            float q0 = 0.f, q1 = 0.f, q2 = 0.f, q3 = 0.f;
            #pragma unroll
            for (int z = 0; z < 8; z += 4) {
                q0 += p[(z + 0) * NN]; q1 += p[(z + 1) * NN];
                q2 += p[(z + 2) * NN]; q3 += p[(z + 3) * NN];
            }
            float s = (q0 + q1) + (q2 + q3);
            s += __shfl_xor(s, 1, 64);
            s += __shfl_xor(s, 2, 64);
            if (sub == 0)
                ncls[i * NSTR + j] = fmaxf(sqA_l[gr] + sqB_l[gc] - 2.f * s, 0.f);
        }
    }
    __syncthreads();

    // ---------------- wave-0 JV solver --------------------------------------
    double val = 0.0;
    if (tid < 64) {
        const int lane = tid;
        const int n_ = sn, m_ = sm;
        const int W = (m_ <= 16) ? 16 : (m_ <= 32 ? 32 : 64);
        const bool cA = (lane < m_), rA = (lane < n_);

        double u = 0.0;
        if (rA) {
            float mx = 0.f;
            const float* row = &ncls[lane * NSTR];
            for (int j = 0; j < m_; ++j) mx = fmaxf(mx, row[j]);
            u = -(double)mx;
        }
        double v = 1e30;
        for (int i = 0; i < n_; ++i) {
            double ui = __shfl(u, i, 64);
            if (cA) v = fmin(v, -(double)ncls[i * NSTR + lane] - ui);
        }
        if (cA) clm[lane] = 0x7fffffff;
        wave_fence();
        int jc = -1;
        for (int j = 0; j < m_; ++j) {
            double vj = __shfl(v, j, 64);
            if (rA && jc < 0) {
                double s = -(double)ncls[lane * NSTR + j] - u - vj;
                if (s < 1e-7) jc = j;
            }
        }
        if (rA && jc >= 0) atomicMin(&clm[jc], lane);
        wave_fence();
        int p = -1;
        if (cA && clm[lane] != 0x7fffffff) p = clm[lane];
        bool rowm = (rA && jc >= 0 && clm[jc] == lane);

        for (int ir = 0; ir < n_; ++ir) {
            if (__shfl(rowm ? 1 : 0, ir, 64)) continue;
            double minv = 1e30, markD = -1.0, ent = -1.0;
            bool used = false; int way = -2;
            if (rA && lane == ir) ent = 0.0;
            double D = 0.0;
            int i0 = ir, jprev = -1;
            int guard = 2 * m_ + 8;
            while (guard-- > 0) {
                double ui = __shfl(u, i0, 64);
                if (cA && !used) {
                    double cand = D - ui - (double)ncls[i0 * NSTR + lane] - v;
                    if (cand < minv) { minv = cand; way = jprev; }
                }
                double kd = (cA && !used) ? embed_key(minv, lane) : 1e30;
                for (int oo = 1; oo < W; oo <<= 1) kd = fmin(kd, __shfl_xor(kd, oo, 64));
                long long kb = __double_as_longlong(kd);
                int j1 = (int)(kb & 127);
                double Dn = __longlong_as_double(kb & ~127LL);
                if (Dn > 1e29) break;
                D = Dn;
                int i1 = __shfl(p, j1, 64);
                if (i1 < 0) {                 // free col: augment along way[]
                    int jj = j1;
                    while (true) {
                        int wp = __shfl(way, jj, 64);
                        int pn = (wp < 0) ? ir : __shfl(p, wp, 64);
                        if (cA && lane == jj) p = pn;
                        if (wp < 0) break;
                        jj = wp;
                    }
                    if (rA && lane == ir) rowm = true;
                    break;
                }
                if (cA && lane == j1) { used = true; markD = D; }
                if (rA && lane == i1) ent = D;
                jprev = j1; i0 = i1;
            }
            if (rA && ent   >= 0.0) u += D - ent;
            if (cA && markD >= 0.0) v -= D - markD;
        }
        if (cA && p >= 0) val = (double)ncls[p * NSTR + lane];
        #pragma unroll
        for (int oo = 1; oo < 64; oo <<= 1) val += __shfl_xor(val, oo, 64);
    }
    if (tid == 0) cls_val[blk] = val;
}

// ---------------- Stage 3: sum class values + rare block-wide fallback ------
__global__ __launch_bounds__(1024) void finalize_kernel(const float* __restrict__ gm,
                                                        const int* __restrict__ flagarr,
                                                        const int* __restrict__ t1,
                                                        const int* __restrict__ t2,
                                                        const double* __restrict__ cls_val,
                                                        float* __restrict__ out) {
    __shared__ float gml[N * GSTRIDE];
    __shared__ int lbl1[N], lbl2[N];
    __shared__ int rowlist[N], collist[N];
    __shared__ int rcnt[64], ccnt[64], rstart[65], cstart[65], rcur[64], ccur[64];
    __shared__ int bigtasks[65];
    __shared__ int nbig_s, flag_s;
    __shared__ double ub[N + 1], vbp[N + 1], minvb[N + 1];
    __shared__ int pb[N + 1], wayb[N + 1], usedb[N + 1];
    __shared__ double redv[NW];
    __shared__ int redi[NW];
    __shared__ double big_total, small_sum;
    __shared__ int jfin_s;

    const int tid = threadIdx.x;
    if (tid < 64) { rcnt[tid] = 0; ccnt[tid] = 0; rcur[tid] = 0; ccur[tid] = 0; }
    if (tid == 0) { nbig_s = 0; flag_s = 0; big_total = 0.0; }
    if (tid < N)  { lbl1[tid] = t1[tid]; lbl2[tid] = t2[tid]; }
    __syncthreads();
    if (tid < 64 && flagarr[tid]) atomicOr(&flag_s, 1);
    if (tid < N) {
        atomicAdd(&rcnt[lbl1[tid] & 63], 1);
        atomicAdd(&ccnt[lbl2[tid] & 63], 1);
    }
    double sv = (tid < 64) ? cls_val[tid] : 0.0;
    __syncthreads();
    if (tid < 64) {
        int rs_ = rcnt[tid], cs_ = ccnt[tid];
        #pragma unroll
        for (int o = 1; o < 64; o <<= 1) {
            int tr = __shfl_up(rs_, o, 64);
            int tc = __shfl_up(cs_, o, 64);
            if (tid >= o) { rs_ += tr; cs_ += tc; }
        }
        rstart[tid + 1] = rs_;
        cstart[tid + 1] = cs_;
        if (tid == 0) { rstart[0] = 0; cstart[0] = 0; }
        if (!flag_s) {
            int R = rcnt[tid], C = ccnt[tid];
            bool big = (R > 0) && (C > 0) && ((R > 64) || (C > 64));
            unsigned long long mb = __ballot(big);
            if (big) bigtasks[__popcll(mb & ((1ull << tid) - 1))] = tid;
            if (tid == 0) nbig_s = __popcll(mb);
        } else if (tid == 0) { nbig_s = 1; bigtasks[0] = -1; }
        if (flag_s) sv = 0.0;
        #pragma unroll
        for (int o = 1; o < 64; o <<= 1) sv += __shfl_xor(sv, o, 64);
        if (tid == 0) small_sum = sv;
    }
    __syncthreads();

    const int nbig = nbig_s;
    if (nbig > 0) {
        if (tid < N) {       // counting-sort scatter
            int l1 = lbl1[tid] & 63;
            int p = atomicAdd(&rcur[l1], 1);
            rowlist[rstart[l1] + p] = tid;
            int l2 = lbl2[tid] & 63;
            int q = atomicAdd(&ccur[l2], 1);
            collist[cstart[l2] + q] = tid;
        }
        __syncthreads();
        #pragma unroll
        for (int pch = 0; pch < 16; ++pch) {
            int e = tid + pch * 1024;
            int i = e >> 7, j = e & 127;
            gml[i * GSTRIDE + j] = gm[rowlist[i] * N + collist[j]];
        }
        __syncthreads();

        for (int bt = 0; bt < nbig; ++bt) {
            const int c = bigtasks[bt];
            int Rn, Cn, rs, cs;
            if (c < 0) { Rn = N; Cn = N; rs = 0; cs = 0; }
            else { Rn = rcnt[c]; Cn = ccnt[c]; rs = rstart[c]; cs = cstart[c]; }
            const bool T = (Rn > Cn);
            const int n_ = T ? Cn : Rn, m_ = T ? Rn : Cn;
            const int rstep = T ? 1 : GSTRIDE;
            const int cstep = T ? GSTRIDE : 1;
            const int rb00 = T ? cs : rs * GSTRIDE;
            const int ob00 = T ? rs * GSTRIDE : cs;
            auto cost = [&](int i, int j) -> double {
                return -(double)gml[rb00 + i * rstep + ob00 + j * cstep];
            };
            for (int x = tid; x <= m_; x += 1024) { vbp[x] = 0.0; pb[x] = 0; }
            for (int x = tid; x <= n_; x += 1024) { ub[x] = 0.0; }
            __syncthreads();
            for (int i = 1; i <= n_; ++i) {
                if (tid == 0) pb[0] = i;
                for (int x = tid; x <= m_; x += 1024) { minvb[x] = 1e300; usedb[x] = 0; }
                __syncthreads();
                int j0 = 0;
                int guard = 2 * m_ + 8;
                while (guard-- > 0) {
                    if (tid == 0) usedb[j0] = 1;
                    __syncthreads();
                    const int i0 = pb[j0];
                    double dl = 1e300; int jl = 0;
                    if (tid < m_) {
                        int j = tid + 1;
                        if (!usedb[j]) {
                            double cur = cost(i0 - 1, j - 1) - ub[i0] - vbp[j];
                            if (cur < minvb[j]) { minvb[j] = cur; wayb[j] = j0; }
                            dl = minvb[j]; jl = j;
                        }
                    }
                    double rv = dl; int ri = jl;
                    #pragma unroll
                    for (int o = 32; o > 0; o >>= 1) {
                        double ov = __shfl_down(rv, o, 64);
                        int oi2 = __shfl_down(ri, o, 64);
                        if (ov < rv) { rv = ov; ri = oi2; }
                    }
                    if ((tid & 63) == 0) { redv[tid >> 6] = rv; redi[tid >> 6] = ri; }
                    __syncthreads();
                    if (tid == 0) {
                        double bd = 1e300; int bj = 0;
                        for (int q = 0; q < NW; ++q) if (redv[q] < bd) { bd = redv[q]; bj = redi[q]; }
                        redv[0] = bd; redi[0] = bj;
                    }
                    __syncthreads();
                    const double delta = redv[0];
                    const int j1 = redi[0];
                    if (tid < m_) {
                        int j = tid + 1;
                        if (usedb[j]) { ub[pb[j]] += delta; vbp[j] -= delta; }
                        else          { minvb[j] -= delta; }
                    }
                    if (tid == 0) ub[pb[0]] += delta;
                    __syncthreads();
                    j0 = j1;
                    if (pb[j0] == 0) break;
                }
                if (tid == 0) jfin_s = j0;
                __syncthreads();
                if (tid == 0) {
                    int jj = jfin_s;
                    while (jj) { int jp = wayb[jj]; pb[jj] = pb[jp]; jj = jp; }
                }
                __syncthreads();
            }
            double bl = 0.0;
            if (tid < m_) { int j = tid + 1; if (pb[j] != 0) bl = -cost(pb[j] - 1, j - 1); }
            #pragma unroll
            for (int o = 32; o > 0; o >>= 1) bl += __shfl_down(bl, o, 64);
            if ((tid & 63) == 0) redv[tid >> 6] = bl;
            __syncthreads();
            if (tid == 0) { double s = 0; for (int q = 0; q < NW; ++q) s += redv[q]; big_total += s; }
            __syncthreads();
        }
    }

    if (tid == 0) out[0] = (float)((small_sum + big_total) / (double)N);
}

extern "C" void kernel_launch(void* const* d_in, const int* in_sizes, int n_in,
                              void* d_out, int out_size, void* d_ws, size_t ws_size,
                              hipStream_t stream) {
    const float* A  = (const float*)d_in[0];
    const float* B  = (const float*)d_in[1];
    const int*   t1 = (const int*)d_in[2];
    const int*   t2 = (const int*)d_in[3];
    float* out = (float*)d_out;
    float* d2p = (float*)d_ws;                        // [32][16384] dot partials, 2 MB
    float* gm  = d2p + ZSPLIT * NN;                   // [128][128] gm
    int*   flagarr = (int*)(gm + NN);                 // [64]
    double* cls_val = (double*)(flagarr + 64);        // [64] (8B aligned)
    float* sqAp = (float*)(cls_val + 64);             // [32][128] row-norm partials
    float* sqBp = sqAp + ZSPLIT * 128;                // [32][128] col-norm partials

    d2_partial<<<dim3(4, 4, ZSPLIT), 256, 0, stream>>>(A, B, d2p, sqAp, sqBp);
    reduce_solve<<<64, 256, 0, stream>>>(d2p, sqAp, sqBp, t1, t2, gm, flagarr, cls_val);
    finalize_kernel<<<1, 1024, 0, stream>>>(gm, flagarr, t1, t2, cls_val, out);
}

// Round 7
// 88.098 us; speedup vs baseline: 1.0576x; 1.0576x over previous
//
#include <hip/hip_runtime.h>

#define N 128
#define DIM 8192
#define NN (N * N)      // 16384
#define ZSPLIT 64
#define NW 16           // waves in finalize block
#define GSTRIDE 130     // LDS gm row stride (fallback solver)
#define NSTR 65         // per-class LDS row stride: 65%32=1 -> conflict-free col reads

// ---------------- wave-sync helpers ----------------------------------------
__device__ __forceinline__ void wave_fence() {
    __threadfence_block();
    __builtin_amdgcn_wave_barrier();
}
__device__ __forceinline__ double embed_key(double v, int j) {
    long long b = __double_as_longlong(v);
    return __longlong_as_double((b & ~127LL) | (long long)j);
}

// ---------------- Stage 1: d2 partials (split-K, no atomics) ----------------
// grid (4,4,64): 32x32 tile, K-chunk 128. 2x2 register tile per thread.
__global__ __launch_bounds__(256) void d2_partial(const float* __restrict__ A,
                                                  const float* __restrict__ B,
                                                  float* __restrict__ d2p) {
    __shared__ float As[32][68];
    __shared__ float Bk[64][36];
    const int tid = threadIdx.x;
    const int bi = blockIdx.x, bj = blockIdx.y, bz = blockIdx.z;
    const int tx = tid & 15, ty = tid >> 4;
    const int row0 = bi * 32, col0 = bj * 32;
    const int kbase = bz * 128;
    float a00 = 0.f, a01 = 0.f, a10 = 0.f, a11 = 0.f;

    for (int it = 0; it < 2; ++it) {
        const int k0 = kbase + it * 64;
        __syncthreads();
        #pragma unroll
        for (int s = 0; s < 2; ++s) {
            int e = tid + s * 256;
            int r = e >> 4, q = e & 15;
            *(float4*)&As[r][q * 4] = *(const float4*)&A[(row0 + r) * DIM + k0 + q * 4];
        }
        #pragma unroll
        for (int s = 0; s < 2; ++s) {
            int r = tid & 31;
            int kq = (tid >> 5) + s * 8;
            float4 b4 = *(const float4*)&B[(col0 + r) * DIM + k0 + kq * 4];
            Bk[kq * 4 + 0][r] = b4.x;
            Bk[kq * 4 + 1][r] = b4.y;
            Bk[kq * 4 + 2][r] = b4.z;
            Bk[kq * 4 + 3][r] = b4.w;
        }
        __syncthreads();
        #pragma unroll
        for (int kk = 0; kk < 64; kk += 4) {
            float x0[4], x1[4];
            *(float4*)x0 = *(const float4*)&As[2 * ty][kk];
            *(float4*)x1 = *(const float4*)&As[2 * ty + 1][kk];
            float y[4][2];
            #pragma unroll
            for (int q = 0; q < 4; ++q)
                *(float2*)y[q] = *(const float2*)&Bk[kk + q][2 * tx];
            #pragma unroll
            for (int q = 0; q < 4; ++q) {
                float d;
                d = x0[q] - y[q][0]; a00 = fmaf(d, d, a00);
                d = x0[q] - y[q][1]; a01 = fmaf(d, d, a01);
                d = x1[q] - y[q][0]; a10 = fmaf(d, d, a10);
                d = x1[q] - y[q][1]; a11 = fmaf(d, d, a11);
            }
        }
    }
    const int o0 = (row0 + 2 * ty) * N + col0 + 2 * tx;
    float* dst = d2p + bz * NN;
    *(float2*)&dst[o0]     = make_float2(a00, a01);
    *(float2*)&dst[o0 + N] = make_float2(a10, a11);
}

// ---------------- Stage 1.5: z-reduce + transform -> gm ---------------------
__global__ __launch_bounds__(256) void reduce_gm(const float* __restrict__ d2p,
                                                 const int* __restrict__ t1,
                                                 const int* __restrict__ t2,
                                                 float* __restrict__ gm,
                                                 int* __restrict__ flagarr) {
    __shared__ int bf;
    if (threadIdx.x == 0) bf = 0;
    __syncthreads();
    const int o = blockIdx.x * 256 + threadIdx.x;
    float s0 = 0.f, s1 = 0.f, s2 = 0.f, s3 = 0.f, s4 = 0.f, s5 = 0.f, s6 = 0.f, s7 = 0.f;
    const float* p = d2p + o;
    #pragma unroll
    for (int z = 0; z < ZSPLIT; z += 8) {
        s0 += p[(z + 0) * NN]; s1 += p[(z + 1) * NN];
        s2 += p[(z + 2) * NN]; s3 += p[(z + 3) * NN];
        s4 += p[(z + 4) * NN]; s5 += p[(z + 5) * NN];
        s6 += p[(z + 6) * NN]; s7 += p[(z + 7) * NN];
    }
    float s = ((s0 + s1) + (s2 + s3)) + ((s4 + s5) + (s6 + s7));
    const int i = o >> 7, j = o & 127;
    const int l1 = t1[i], l2 = t2[j];
    const bool same = (l1 == l2);
    float g = same ? fmaxf(s, 0.f) : fmaxf(200.f - s, 0.f);
    gm[o] = g;
    bool bad = (!same && g > 0.f) || l1 < 0 || l1 > 63 || l2 < 0 || l2 > 63;
    unsigned long long m = __ballot(bad);
    if ((threadIdx.x & 63) == 0 && m) atomicOr(&bf, 1);
    __syncthreads();
    if (threadIdx.x == 0) flagarr[blockIdx.x] = bf;
}

// ---------------- Stage 2a: per-class Hungarian, one wave-block per class ---
// 64 blocks x 64 threads. Each block redundantly derives the decomposition
// from t1/t2 (ballot histogram + compaction), stages only its own class
// submatrix into LDS, and runs the wave JV solver with width-adaptive
// butterflies. All 64 cls_val slots are written (poison-safe).
__global__ __launch_bounds__(64) void solve_classes(const float* __restrict__ gm,
                                                    const int* __restrict__ flagarr,
                                                    const int* __restrict__ t1,
                                                    const int* __restrict__ t2,
                                                    double* __restrict__ cls_val) {
    __shared__ float ncls[64 * NSTR];   // 16.6 KB, row stride 65
    __shared__ int rowl[64], coll[64];
    __shared__ int rcnt[64], ccnt[64];
    __shared__ int tasks[64];
    __shared__ int clm[64];

    const int lane = threadIdx.x;
    const int l1a = t1[lane] & 63, l1b = t1[lane + 64] & 63;
    const int l2a = t2[lane] & 63, l2b = t2[lane + 64] & 63;
    const int fl  = flagarr[lane];
    rcnt[lane] = 0; ccnt[lane] = 0;
    __syncthreads();
    atomicAdd(&rcnt[l1a], 1); atomicAdd(&rcnt[l1b], 1);
    atomicAdd(&ccnt[l2a], 1); atomicAdd(&ccnt[l2b], 1);
    __syncthreads();
    const bool flag = (__ballot(fl != 0) != 0ull);
    int ntasks;
    {
        int R = rcnt[lane], C = ccnt[lane];
        bool small = (!flag) && (R > 0) && (C > 0) && (R <= 64) && (C <= 64);
        unsigned long long ms = __ballot(small);
        if (small) tasks[__popcll(ms & ((1ull << lane) - 1))] = lane;
        ntasks = (int)__popcll(ms);
    }
    __syncthreads();
    if ((int)blockIdx.x >= ntasks) {
        if (lane == 0) cls_val[blockIdx.x] = 0.0;
        return;
    }
    const int c = tasks[blockIdx.x];

    // compact this class's row/col index lists via ballots
    const unsigned long long mlt = (1ull << lane) - 1;
    unsigned long long b1 = __ballot(l1a == c);
    unsigned long long b2 = __ballot(l1b == c);
    if (l1a == c) rowl[__popcll(b1 & mlt)] = lane;
    if (l1b == c) rowl[__popcll(b1) + __popcll(b2 & mlt)] = lane + 64;
    const int Rn = (int)(__popcll(b1) + __popcll(b2));
    unsigned long long c1 = __ballot(l2a == c);
    unsigned long long c2 = __ballot(l2b == c);
    if (l2a == c) coll[__popcll(c1 & mlt)] = lane;
    if (l2b == c) coll[__popcll(c1) + __popcll(c2 & mlt)] = lane + 64;
    const int Cn = (int)(__popcll(c1) + __popcll(c2));
    __syncthreads();

    // stage normalized (n_ <= m_) class submatrix
    const bool T  = (Rn > Cn);
    const int n_  = T ? Cn : Rn;
    const int m_  = T ? Rn : Cn;
    const int tot = n_ * m_;
    for (int e = lane; e < tot; e += 64) {
        int i = e / m_, j = e - i * m_;
        int gr = T ? rowl[j] : rowl[i];
        int gc = T ? coll[i] : coll[j];
        ncls[i * NSTR + j] = gm[gr * N + gc];
    }
    __syncthreads();

    const int W = (m_ <= 16) ? 16 : (m_ <= 32 ? 32 : 64);
    const bool cA = (lane < m_), rA = (lane < n_);

    // row reduction: u = -max_j cls(row=lane, j)
    double u = 0.0;
    if (rA) {
        float mx = 0.f;
        const float* row = &ncls[lane * NSTR];
        for (int j = 0; j < m_; ++j) mx = fmaxf(mx, row[j]);
        u = -(double)mx;
    }
    // col reduction: v = min_i (-cls(i, col=lane) - u_i)
    double v = 1e30;
    for (int i = 0; i < n_; ++i) {
        double ui = __shfl(u, i, 64);
        if (cA) v = fmin(v, -(double)ncls[i * NSTR + lane] - ui);
    }
    // greedy tight assignment
    if (cA) clm[lane] = 0x7fffffff;
    wave_fence();
    int jc = -1;
    for (int j = 0; j < m_; ++j) {
        double vj = __shfl(v, j, 64);
        if (rA && jc < 0) {
            double s = -(double)ncls[lane * NSTR + j] - u - vj;
            if (s < 1e-7) jc = j;
        }
    }
    if (rA && jc >= 0) atomicMin(&clm[jc], lane);
    wave_fence();
    int p = -1;
    if (cA && clm[lane] != 0x7fffffff) p = clm[lane];
    bool rowm = (rA && jc >= 0 && clm[jc] == lane);

    // augmentation phases (JV)
    for (int ir = 0; ir < n_; ++ir) {
        if (__shfl(rowm ? 1 : 0, ir, 64)) continue;
        double minv = 1e30, markD = -1.0, ent = -1.0;
        bool used = false; int way = -2;
        if (rA && lane == ir) ent = 0.0;
        double D = 0.0;
        int i0 = ir, jprev = -1;
        int guard = 2 * m_ + 8;
        while (guard-- > 0) {
            double ui = __shfl(u, i0, 64);
            if (cA && !used) {
                double cand = D - ui - (double)ncls[i0 * NSTR + lane] - v;
                if (cand < minv) { minv = cand; way = jprev; }
            }
            double kd = (cA && !used) ? embed_key(minv, lane) : 1e30;
            for (int o = 1; o < W; o <<= 1) kd = fmin(kd, __shfl_xor(kd, o, 64));
            long long kb = __double_as_longlong(kd);
            int j1 = (int)(kb & 127);
            double Dn = __longlong_as_double(kb & ~127LL);
            if (Dn > 1e29) break;
            D = Dn;
            int i1 = __shfl(p, j1, 64);
            if (i1 < 0) {                 // free col: augment along way[]
                int jj = j1;
                while (true) {
                    int wp = __shfl(way, jj, 64);
                    int pn = (wp < 0) ? ir : __shfl(p, wp, 64);
                    if (cA && lane == jj) p = pn;
                    if (wp < 0) break;
                    jj = wp;
                }
                if (rA && lane == ir) rowm = true;
                break;
            }
            if (cA && lane == j1) { used = true; markD = D; }
            if (rA && lane == i1) ent = D;
            jprev = j1; i0 = i1;
        }
        if (rA && ent   >= 0.0) u += D - ent;
        if (cA && markD >= 0.0) v -= D - markD;
    }

    // class value
    double val = 0.0;
    if (cA && p >= 0) val = (double)ncls[p * NSTR + lane];
    #pragma unroll
    for (int o = 1; o < 64; o <<= 1) val += __shfl_xor(val, o, 64);
    if (lane == 0) cls_val[blockIdx.x] = val;
}

// ---------------- Stage 2b: sum class values + rare block-wide fallback -----
__global__ __launch_bounds__(1024) void finalize_kernel(const float* __restrict__ gm,
                                                        const int* __restrict__ flagarr,
                                                        const int* __restrict__ t1,
                                                        const int* __restrict__ t2,
                                                        const double* __restrict__ cls_val,
                                                        float* __restrict__ out) {
    __shared__ float gml[N * GSTRIDE];
    __shared__ int lbl1[N], lbl2[N];
    __shared__ int rowlist[N], collist[N];
    __shared__ int rcnt[64], ccnt[64], rstart[65], cstart[65], rcur[64], ccur[64];
    __shared__ int bigtasks[65];
    __shared__ int nbig_s, flag_s;
    __shared__ double ub[N + 1], vbp[N + 1], minvb[N + 1];
    __shared__ int pb[N + 1], wayb[N + 1], usedb[N + 1];
    __shared__ double redv[NW];
    __shared__ int redi[NW];
    __shared__ double big_total, small_sum;
    __shared__ int jfin_s;

    const int tid = threadIdx.x;
    if (tid < 64) { rcnt[tid] = 0; ccnt[tid] = 0; rcur[tid] = 0; ccur[tid] = 0; }
    if (tid == 0) { nbig_s = 0; flag_s = 0; big_total = 0.0; }
    if (tid < N)  { lbl1[tid] = t1[tid]; lbl2[tid] = t2[tid]; }
    __syncthreads();
    if (tid < 64 && flagarr[tid]) atomicOr(&flag_s, 1);
    if (tid < N) {
        atomicAdd(&rcnt[lbl1[tid] & 63], 1);
        atomicAdd(&ccnt[lbl2[tid] & 63], 1);
    }
    double sv = (tid < 64) ? cls_val[tid] : 0.0;
    __syncthreads();
    if (tid < 64) {
        int rs_ = rcnt[tid], cs_ = ccnt[tid];
        #pragma unroll
        for (int o = 1; o < 64; o <<= 1) {
            int tr = __shfl_up(rs_, o, 64);
            int tc = __shfl_up(cs_, o, 64);
            if (tid >= o) { rs_ += tr; cs_ += tc; }
        }
        rstart[tid + 1] = rs_;
        cstart[tid + 1] = cs_;
        if (tid == 0) { rstart[0] = 0; cstart[0] = 0; }
        if (!flag_s) {
            int R = rcnt[tid], C = ccnt[tid];
            bool big = (R > 0) && (C > 0) && ((R > 64) || (C > 64));
            unsigned long long mb = __ballot(big);
            if (big) bigtasks[__popcll(mb & ((1ull << tid) - 1))] = tid;
            if (tid == 0) nbig_s = __popcll(mb);
        } else if (tid == 0) { nbig_s = 1; bigtasks[0] = -1; }
        if (flag_s) sv = 0.0;
        #pragma unroll
        for (int o = 1; o < 64; o <<= 1) sv += __shfl_xor(sv, o, 64);
        if (tid == 0) small_sum = sv;
    }
    __syncthreads();

    const int nbig = nbig_s;
    if (nbig > 0) {
        if (tid < N) {       // counting-sort scatter
            int l1 = lbl1[tid] & 63;
            int p = atomicAdd(&rcur[l1], 1);
            rowlist[rstart[l1] + p] = tid;
            int l2 = lbl2[tid] & 63;
            int q = atomicAdd(&ccur[l2], 1);
            collist[cstart[l2] + q] = tid;
        }
        __syncthreads();
        #pragma unroll
        for (int pch = 0; pch < 16; ++pch) {
            int e = tid + pch * 1024;
            int i = e >> 7, j = e & 127;
            gml[i * GSTRIDE + j] = gm[rowlist[i] * N + collist[j]];
        }
        __syncthreads();

        for (int bt = 0; bt < nbig; ++bt) {
            const int c = bigtasks[bt];
            int Rn, Cn, rs, cs;
            if (c < 0) { Rn = N; Cn = N; rs = 0; cs = 0; }
            else { Rn = rcnt[c]; Cn = ccnt[c]; rs = rstart[c]; cs = cstart[c]; }
            const bool T = (Rn > Cn);
            const int n_ = T ? Cn : Rn, m_ = T ? Rn : Cn;
            const int rstep = T ? 1 : GSTRIDE;
            const int cstep = T ? GSTRIDE : 1;
            const int rb00 = T ? cs : rs * GSTRIDE;
            const int ob00 = T ? rs * GSTRIDE : cs;
            auto cost = [&](int i, int j) -> double {
                return -(double)gml[rb00 + i * rstep + ob00 + j * cstep];
            };
            for (int x = tid; x <= m_; x += 1024) { vbp[x] = 0.0; pb[x] = 0; }
            for (int x = tid; x <= n_; x += 1024) { ub[x] = 0.0; }
            __syncthreads();
            for (int i = 1; i <= n_; ++i) {
                if (tid == 0) pb[0] = i;
                for (int x = tid; x <= m_; x += 1024) { minvb[x] = 1e300; usedb[x] = 0; }
                __syncthreads();
                int j0 = 0;
                int guard = 2 * m_ + 8;
                while (guard-- > 0) {
                    if (tid == 0) usedb[j0] = 1;
                    __syncthreads();
                    const int i0 = pb[j0];
                    double dl = 1e300; int jl = 0;
                    if (tid < m_) {
                        int j = tid + 1;
                        if (!usedb[j]) {
                            double cur = cost(i0 - 1, j - 1) - ub[i0] - vbp[j];
                            if (cur < minvb[j]) { minvb[j] = cur; wayb[j] = j0; }
                            dl = minvb[j]; jl = j;
                        }
                    }
                    double rv = dl; int ri = jl;
                    #pragma unroll
                    for (int o = 32; o > 0; o >>= 1) {
                        double ov = __shfl_down(rv, o, 64);
                        int oi2 = __shfl_down(ri, o, 64);
                        if (ov < rv) { rv = ov; ri = oi2; }
                    }
                    if ((tid & 63) == 0) { redv[tid >> 6] = rv; redi[tid >> 6] = ri; }
                    __syncthreads();
                    if (tid == 0) {
                        double bd = 1e300; int bj = 0;
                        for (int q = 0; q < NW; ++q) if (redv[q] < bd) { bd = redv[q]; bj = redi[q]; }
                        redv[0] = bd; redi[0] = bj;
                    }
                    __syncthreads();
                    const double delta = redv[0];
                    const int j1 = redi[0];
                    if (tid < m_) {
                        int j = tid + 1;
                        if (usedb[j]) { ub[pb[j]] += delta; vbp[j] -= delta; }
                        else          { minvb[j] -= delta; }
                    }
                    if (tid == 0) ub[pb[0]] += delta;
                    __syncthreads();
                    j0 = j1;
                    if (pb[j0] == 0) break;
                }
                if (tid == 0) jfin_s = j0;
                __syncthreads();
                if (tid == 0) {
                    int jj = jfin_s;
                    while (jj) { int jp = wayb[jj]; pb[jj] = pb[jp]; jj = jp; }
                }
                __syncthreads();
            }
            double bl = 0.0;
            if (tid < m_) { int j = tid + 1; if (pb[j] != 0) bl = -cost(pb[j] - 1, j - 1); }
            #pragma unroll
            for (int o = 32; o > 0; o >>= 1) bl += __shfl_down(bl, o, 64);
            if ((tid & 63) == 0) redv[tid >> 6] = bl;
            __syncthreads();
            if (tid == 0) { double s = 0; for (int q = 0; q < NW; ++q) s += redv[q]; big_total += s; }
            __syncthreads();
        }
    }

    if (tid == 0) out[0] = (float)((small_sum + big_total) / (double)N);
}

extern "C" void kernel_launch(void* const* d_in, const int* in_sizes, int n_in,
                              void* d_out, int out_size, void* d_ws, size_t ws_size,
                              hipStream_t stream) {
    const float* A  = (const float*)d_in[0];
    const float* B  = (const float*)d_in[1];
    const int*   t1 = (const int*)d_in[2];
    const int*   t2 = (const int*)d_in[3];
    float* out = (float*)d_out;
    float* d2p = (float*)d_ws;                        // [64][16384] partials, 4 MB
    float* gm  = (float*)d_ws + ZSPLIT * NN;          // [128][128] gm, 64 KB
    int*   flagarr = (int*)(gm + NN);                 // [64] cross-label flags
    double* cls_val = (double*)(flagarr + 64);        // [64] per-class values (8B-aligned)

    d2_partial<<<dim3(4, 4, ZSPLIT), 256, 0, stream>>>(A, B, d2p);
    reduce_gm<<<64, 256, 0, stream>>>(d2p, t1, t2, gm, flagarr);
    solve_classes<<<64, 64, 0, stream>>>(gm, flagarr, t1, t2, cls_val);
    finalize_kernel<<<1, 1024, 0, stream>>>(gm, flagarr, t1, t2, cls_val, out);
}